// Round 3
// baseline (5581.037 us; speedup 1.0000x reference)
//
#include <hip/hip_runtime.h>
#include <math.h>

#define Hn 256
#define Wn 256
#define Cn 64
#define Mk 12
#define NM 24
#define FCH 128
#define HW 65536

__device__ __forceinline__ float gelu_exact(float x) {
    return 0.5f * x * (1.0f + erff(x * 0.7071067811865476f));
}

// ---------------- tables ----------------
__global__ __launch_bounds__(256) void k_init_tables(float* tc, float* ts,
                                                     float* twc, float* tws) {
    int i = threadIdx.x;  // 0..255
    const float step = 0.024543692606170259f;  // 2*pi/256
    tc[i] = cosf(i * step);
    ts[i] = sinf(i * step);
    for (int k = 0; k < Mk; ++k) {
        int idx = (i * k) & 255;
        twc[i * Mk + k] = cosf(idx * step);
        tws[i * Mk + k] = sinf(idx * step);
    }
}

__global__ __launch_bounds__(256) void k_transpose_fc1(const float* __restrict__ fc1w,
                                                       float* __restrict__ fc1T) {
    int t = blockIdx.x * blockDim.x + threadIdx.x;  // < 8192
    int d = t % FCH, c = t / FCH;
    fc1T[d * Cn + c] = fc1w[c * FCH + d];
}

// ------- DFT along W of x (all 16 batches, 4096 rows), lane-per-row -------
__global__ __launch_bounds__(64) void k_dftw_x(const float* __restrict__ x,
                                               float* __restrict__ Xxw,
                                               const float* __restrict__ twc,
                                               const float* __restrict__ tws) {
    int r = blockIdx.x * 64 + threadIdx.x;  // 0..4095
    const float* hp = x + (size_t)r * Wn;
    float xr[Mk], xi[Mk];
#pragma unroll
    for (int k = 0; k < Mk; ++k) { xr[k] = 0.f; xi[k] = 0.f; }
    for (int w4 = 0; w4 < 64; ++w4) {
        float4 v = ((const float4*)hp)[w4];
        float vv[4] = {v.x, v.y, v.z, v.w};
#pragma unroll
        for (int j = 0; j < 4; ++j) {
            int wbase = (w4 * 4 + j) * Mk;  // wave-uniform -> scalar loads
#pragma unroll
            for (int k = 0; k < Mk; ++k) {
                xr[k] += vv[j] * twc[wbase + k];
                xi[k] -= vv[j] * tws[wbase + k];
            }
        }
    }
    float* op = Xxw + (size_t)r * (2 * Mk);
#pragma unroll
    for (int k = 0; k < Mk; ++k) { op[2 * k] = xr[k]; op[2 * k + 1] = xi[k]; }
}

// ------- DFT along H of x-modes -> Xfx[b][m][ky] (all batches) -------
__global__ __launch_bounds__(256) void k_xdfth(const float* __restrict__ Xxw,
                                               float* __restrict__ Xfx,
                                               const float* __restrict__ tc,
                                               const float* __restrict__ ts) {
    int t = blockIdx.x * 256 + threadIdx.x;  // < 4608
    if (t >= 16 * 288) return;
    int ky = t % Mk;
    int m  = (t / Mk) % NM;
    int b  = t / 288;
    int kx = (m < Mk) ? m : (232 + m);
    const float* base = Xxw + (size_t)b * Hn * 2 * Mk + 2 * ky;
    float ar = 0.f, ai = 0.f;
    for (int hh = 0; hh < Hn; ++hh) {
        float vr = base[hh * 2 * Mk];
        float vi = base[hh * 2 * Mk + 1];
        int idx = (kx * hh) & 255;
        float c = tc[idx], s = ts[idx];
        ar += vr * c + vi * s;   // * e^{-i theta}
        ai += vi * c - vr * s;
    }
    Xfx[2 * t] = ar;
    Xfx[2 * t + 1] = ai;
}

// ------- layer-0 mix: Z[b][mk][o] from Xfx (lift folded in) -------
__global__ __launch_bounds__(256, 2) void k_mix0(const float* __restrict__ Xfx,
                                                 const float* __restrict__ scw,
                                                 const float* __restrict__ w0,
                                                 const float* __restrict__ b0v,
                                                 float* __restrict__ Z, int b0) {
    __shared__ float red[512];
    int blk = blockIdx.x;
    int b = blk / 288, mk = blk % 288;
    int m = mk / Mk, ky = mk % Mk;
    int t = threadIdx.x;
    int o = t & 63, q = t >> 6;
    float xr = Xfx[((b0 + b) * 288 + mk) * 2];
    float xi = Xfx[((b0 + b) * 288 + mk) * 2 + 1];
    int j = (m < Mk) ? 0 : 1;
    int kxw = (m < Mk) ? m : (m - Mk);
    const float* wb = scw + ((((size_t)j * Cn + q * 16) * Cn + o) * (Mk * Mk) + kxw * Mk + ky) * 2;
    const size_t wstep = (size_t)Cn * Mk * Mk * 2;
    float zr = 0.f, zi = 0.f;
#pragma unroll
    for (int ii = 0; ii < 16; ++ii) {
        int i = q * 16 + ii;
        float ar = w0[i] * xr, ai = w0[i] * xi;
        if (mk == 0) ar += 65536.0f * b0v[i];
        float wr = wb[0], wi = wb[1];
        wb += wstep;
        zr += ar * wr - ai * wi;
        zi += ar * wi + ai * wr;
    }
    red[t * 2] = zr; red[t * 2 + 1] = zi;
    __syncthreads();
    if (t < 64) {
        float sr = red[t * 2] + red[(t + 64) * 2] + red[(t + 128) * 2] + red[(t + 192) * 2];
        float si = red[t * 2 + 1] + red[(t + 64) * 2 + 1] + red[(t + 128) * 2 + 1] + red[(t + 192) * 2 + 1];
        const float sc = 2.0f / 65536.0f;  // hermitian 2x + 1/(H*W), folded here
        Z[((size_t)(b * 288 + mk) * 64 + t) * 2] = sr * sc;
        Z[((size_t)(b * 288 + mk) * 64 + t) * 2 + 1] = si * sc;
    }
}

// ------- layers 1..3: dft_h(Xw) + mode mix, fused -------
__global__ __launch_bounds__(256, 2) void k_dfthmix(const float* __restrict__ Xw,
                                                    const float* __restrict__ scw,
                                                    float* __restrict__ Z,
                                                    const float* __restrict__ tc,
                                                    const float* __restrict__ ts, int l) {
    __shared__ float red[512];
    __shared__ float xf[128];
    int blk = blockIdx.x;
    int b = blk / 288, mk = blk % 288;
    int m = mk / Mk, ky = mk % Mk;
    int t = threadIdx.x;
    int kx = (m < Mk) ? m : (232 + m);
    int i = t & 63, q = t >> 6;
    // phase 1: Xf[i] = sum_hh Xw[hh][i][ky] * e^{-i kx hh}
    const float* xb = Xw + (size_t)b * 393216;
    float ar = 0.f, ai = 0.f;
    for (int hc = 0; hc < 64; ++hc) {
        int hh = q * 64 + hc;
        const float* p = xb + ((size_t)hh * 64 + i) * 24 + 2 * ky;
        float vr = p[0], vi = p[1];
        int idx = (kx * hh) & 255;
        float c = tc[idx], s = ts[idx];
        ar += vr * c + vi * s;
        ai += vi * c - vr * s;
    }
    red[t * 2] = ar; red[t * 2 + 1] = ai;
    __syncthreads();
    if (t < 64) {
        xf[t * 2]     = red[t * 2] + red[(t + 64) * 2] + red[(t + 128) * 2] + red[(t + 192) * 2];
        xf[t * 2 + 1] = red[t * 2 + 1] + red[(t + 64) * 2 + 1] + red[(t + 128) * 2 + 1] + red[(t + 192) * 2 + 1];
    }
    __syncthreads();
    // phase 2: Z[o] = sum_i W[i][o] * Xf[i]
    int o = t & 63;
    int j = (m < Mk) ? 0 : 1;
    int kxw = (m < Mk) ? m : (m - Mk);
    const float* wb = scw + ((((size_t)(l * 2 + j) * Cn + q * 16) * Cn + o) * (Mk * Mk) + kxw * Mk + ky) * 2;
    const size_t wstep = (size_t)Cn * Mk * Mk * 2;
    float zr = 0.f, zi = 0.f;
#pragma unroll
    for (int ii = 0; ii < 16; ++ii) {
        float br = xf[(q * 16 + ii) * 2], bi = xf[(q * 16 + ii) * 2 + 1];
        float wr = wb[0], wi = wb[1];
        wb += wstep;
        zr += br * wr - bi * wi;
        zi += br * wi + bi * wr;
    }
    __syncthreads();
    red[t * 2] = zr; red[t * 2 + 1] = zi;
    __syncthreads();
    if (t < 64) {
        float sr = red[t * 2] + red[(t + 64) * 2] + red[(t + 128) * 2] + red[(t + 192) * 2];
        float si = red[t * 2 + 1] + red[(t + 64) * 2 + 1] + red[(t + 128) * 2 + 1] + red[(t + 192) * 2 + 1];
        const float sc = 2.0f / 65536.0f;
        Z[((size_t)(b * 288 + mk) * 64 + t) * 2] = sr * sc;
        Z[((size_t)(b * 288 + mk) * 64 + t) * 2 + 1] = si * sc;
    }
}

// ------- fused A: idft_h(Z) + idft_w + pointwise + gelu + dft_w(h_new) -------
// xh: x (first=1) or h (first=0; aliases hn -- in-place, per-fiber, reads
// precede writes; no __restrict__ on xh/hn).
__global__ __launch_bounds__(256, 1) void k_fusedA(const float* xh,
        const float* __restrict__ Zb, const float* __restrict__ pww,
        const float* __restrict__ pwb, const float* __restrict__ w0,
        const float* __restrict__ b0v, float* hn, float* __restrict__ XwOut,
        const float* __restrict__ tc, const float* __restrict__ ts,
        const float* __restrict__ twc, const float* __restrict__ tws,
        int l, int first) {
    __shared__ float ext[32 * 257];  // Y (1536 fl) then transpose chunks
    int b  = blockIdx.x >> 8;
    int hh = blockIdx.x & 255;
    int w  = threadIdx.x;
    const float* Zp = Zb + (size_t)b * 288 * 64 * 2;
    // Y[o][ky] = sum_m Z[m*12+ky][o] * e^{+i kx(m) hh}
#pragma unroll
    for (int r3 = 0; r3 < 3; ++r3) {
        int p = w + 256 * r3;          // p = o*12 + ky
        int o = p / Mk, ky = p % Mk;
        float yr = 0.f, yi = 0.f;
#pragma unroll
        for (int m = 0; m < NM; ++m) {
            int kx = (m < Mk) ? m : (232 + m);
            int idx = (kx * hh) & 255;
            float c = tc[idx], s = ts[idx];
            float zr = Zp[((m * Mk + ky) * 64 + o) * 2];
            float zi = Zp[((m * Mk + ky) * 64 + o) * 2 + 1];
            yr += zr * c - zi * s;
            yi += zr * s + zi * c;
        }
        ext[p * 2] = yr; ext[p * 2 + 1] = yi;
    }
    __syncthreads();
    // per-thread rotators cos/sin(2 pi k w / 256)
    float cwv[Mk], swv[Mk];
#pragma unroll
    for (int k = 0; k < Mk; ++k) {
        int idx = (k * w) & 255;
        cwv[k] = tc[idx]; swv[k] = ts[idx];
    }
    float acc[Cn];
#pragma unroll
    for (int o = 0; o < Cn; ++o) {
        const float* yp = ext + o * 24;
        float a = pwb[l * Cn + o] + 0.5f * yp[0];
#pragma unroll
        for (int k = 1; k < Mk; ++k)
            a += yp[2 * k] * cwv[k] - yp[2 * k + 1] * swv[k];
        acc[o] = a;
    }
    // pointwise conv
    const float* wwb = pww + l * Cn * Cn;
    if (first) {
        float xv = xh[(size_t)b * HW + hh * 256 + w];
#pragma unroll 1
        for (int ic = 0; ic < 4; ++ic) {
            float v[16];
#pragma unroll
            for (int j2 = 0; j2 < 16; ++j2)
                v[j2] = w0[ic * 16 + j2] * xv + b0v[ic * 16 + j2];
#pragma unroll
            for (int o = 0; o < Cn; ++o) {
                const float* wr = wwb + o * Cn + ic * 16;
                float a = acc[o];
#pragma unroll
                for (int j2 = 0; j2 < 16; ++j2) a += v[j2] * wr[j2];
                acc[o] = a;
            }
        }
    } else {
        const float* hb = xh + (size_t)b * Cn * HW + hh * 256 + w;
#pragma unroll 1
        for (int ic = 0; ic < 4; ++ic) {
            float v[16];
#pragma unroll
            for (int j2 = 0; j2 < 16; ++j2)
                v[j2] = hb[(size_t)(ic * 16 + j2) * HW];
#pragma unroll
            for (int o = 0; o < Cn; ++o) {
                const float* wr = wwb + o * Cn + ic * 16;
                float a = acc[o];
#pragma unroll
                for (int j2 = 0; j2 < 16; ++j2) a += v[j2] * wr[j2];
                acc[o] = a;
            }
        }
    }
    // gelu + store h
    float* ob = hn + (size_t)b * Cn * HW + hh * 256 + w;
#pragma unroll
    for (int o = 0; o < Cn; ++o) {
        acc[o] = gelu_exact(acc[o]);
        ob[(size_t)o * HW] = acc[o];
    }
    // DFT along W of h_new via LDS transpose (2 chunks of 32 channels)
    float* Xrow = XwOut + (size_t)b * 393216 + (size_t)hh * 64 * 24;
#pragma unroll 1
    for (int oc = 0; oc < 2; ++oc) {
        __syncthreads();  // also guards Y-region reuse on oc==0
#pragma unroll
        for (int o2 = 0; o2 < 32; ++o2) ext[o2 * 257 + w] = acc[oc * 32 + o2];
        __syncthreads();
#pragma unroll 1
        for (int r2 = 0; r2 < 2; ++r2) {
            int p = w + 256 * r2;
            if (p < 384) {
                int o2 = p / Mk, ky = p % Mk;
                const float* row = ext + o2 * 257;
                float xr = 0.f, xi = 0.f;
                for (int wi2 = 0; wi2 < Wn; ++wi2) {
                    float hv = row[wi2];
                    xr += hv * twc[wi2 * Mk + ky];
                    xi -= hv * tws[wi2 * Mk + ky];
                }
                int o = oc * 32 + o2;
                Xrow[o * 24 + 2 * ky] = xr;
                Xrow[o * 24 + 2 * ky + 1] = xi;
            }
        }
    }
}

// ------- fused B (layer 3): idft + pointwise (no gelu) + fc1/gelu/fc2 -------
__global__ __launch_bounds__(256, 1) void k_fusedB(const float* __restrict__ h,
        const float* __restrict__ Zb, const float* __restrict__ pww,
        const float* __restrict__ pwb, const float* __restrict__ fc1T,
        const float* __restrict__ fc1b, const float* __restrict__ fc2w,
        const float* __restrict__ fc2b, float* __restrict__ outp,
        const float* __restrict__ tc, const float* __restrict__ ts) {
    __shared__ float ext[1536];
    int b  = blockIdx.x >> 8;
    int hh = blockIdx.x & 255;
    int w  = threadIdx.x;
    const float* Zp = Zb + (size_t)b * 288 * 64 * 2;
#pragma unroll
    for (int r3 = 0; r3 < 3; ++r3) {
        int p = w + 256 * r3;
        int o = p / Mk, ky = p % Mk;
        float yr = 0.f, yi = 0.f;
#pragma unroll
        for (int m = 0; m < NM; ++m) {
            int kx = (m < Mk) ? m : (232 + m);
            int idx = (kx * hh) & 255;
            float c = tc[idx], s = ts[idx];
            float zr = Zp[((m * Mk + ky) * 64 + o) * 2];
            float zi = Zp[((m * Mk + ky) * 64 + o) * 2 + 1];
            yr += zr * c - zi * s;
            yi += zr * s + zi * c;
        }
        ext[p * 2] = yr; ext[p * 2 + 1] = yi;
    }
    __syncthreads();
    float cwv[Mk], swv[Mk];
#pragma unroll
    for (int k = 0; k < Mk; ++k) {
        int idx = (k * w) & 255;
        cwv[k] = tc[idx]; swv[k] = ts[idx];
    }
    float acc[Cn];
#pragma unroll
    for (int o = 0; o < Cn; ++o) {
        const float* yp = ext + o * 24;
        float a = pwb[3 * Cn + o] + 0.5f * yp[0];
#pragma unroll
        for (int k = 1; k < Mk; ++k)
            a += yp[2 * k] * cwv[k] - yp[2 * k + 1] * swv[k];
        acc[o] = a;
    }
    const float* wwb = pww + 3 * Cn * Cn;
    const float* hb = h + (size_t)b * Cn * HW + hh * 256 + w;
#pragma unroll 1
    for (int ic = 0; ic < 4; ++ic) {
        float v[16];
#pragma unroll
        for (int j2 = 0; j2 < 16; ++j2)
            v[j2] = hb[(size_t)(ic * 16 + j2) * HW];
#pragma unroll
        for (int o = 0; o < Cn; ++o) {
            const float* wr = wwb + o * Cn + ic * 16;
            float a = acc[o];
#pragma unroll
            for (int j2 = 0; j2 < 16; ++j2) a += v[j2] * wr[j2];
            acc[o] = a;
        }
    }
    // fc1 -> gelu -> fc2, streaming over d (no hid[] array)
    float outv = fc2b[0];
#pragma unroll 1
    for (int d = 0; d < FCH; ++d) {
        const float* wr = fc1T + d * Cn;  // uniform -> s_load
        float tv = fc1b[d];
#pragma unroll
        for (int o = 0; o < Cn; ++o) tv += acc[o] * wr[o];
        outv += gelu_exact(tv) * fc2w[d];
    }
    outp[(size_t)b * HW + hh * 256 + w] = outv;
}

extern "C" void kernel_launch(void* const* d_in, const int* in_sizes, int n_in,
                              void* d_out, int out_size, void* d_ws, size_t ws_size,
                              hipStream_t stream) {
    const float* x    = (const float*)d_in[0];
    const float* fc0w = (const float*)d_in[1];
    const float* fc0b = (const float*)d_in[2];
    const float* scw  = (const float*)d_in[3];
    const float* pww  = (const float*)d_in[4];
    const float* pwb  = (const float*)d_in[5];
    const float* fc1w = (const float*)d_in[6];
    const float* fc1b = (const float*)d_in[7];
    const float* fc2w = (const float*)d_in[8];
    const float* fc2b = (const float*)d_in[9];
    float* out = (float*)d_out;
    float* ws  = (float*)d_ws;

    // globals: 24,064 fl; per batch: h 4,194,304 + Xw 393,216 + Z 36,864
    const size_t basef = 24064;
    const size_t perbf = 4624384;
    int bc = 0;
    for (int cand = 16; cand >= 1; cand >>= 1)
        if ((basef + perbf * (size_t)cand) * 4 <= ws_size) { bc = cand; break; }
    if (bc == 0) return;  // diagnosable: zero output

    float* tabc = ws;
    float* tabs = tabc + 256;
    float* twc  = tabs + 256;
    float* tws_ = twc + 3072;
    float* fc1T = tws_ + 3072;
    float* Xfx  = fc1T + 8192;          // 16*288*2 = 9216
    float* hbuf = ws + basef;           // bc * 4,194,304  (also Xxw temp: 98,304)
    float* Xw   = hbuf + (size_t)bc * 4194304;  // bc * 393,216
    float* Zb   = Xw + (size_t)bc * 393216;     // bc * 36,864

    k_init_tables<<<1, 256, 0, stream>>>(tabc, tabs, twc, tws_);
    k_transpose_fc1<<<32, 256, 0, stream>>>(fc1w, fc1T);
    k_dftw_x<<<64, 64, 0, stream>>>(x, hbuf, twc, tws_);       // Xxw in hbuf
    k_xdfth<<<18, 256, 0, stream>>>(hbuf, Xfx, tabc, tabs);

    for (int b0 = 0; b0 < 16; b0 += bc) {
        k_mix0<<<bc * 288, 256, 0, stream>>>(Xfx, scw, fc0w, fc0b, Zb, b0);
        k_fusedA<<<bc * 256, 256, 0, stream>>>(x + (size_t)b0 * HW, Zb, pww, pwb,
                                               fc0w, fc0b, hbuf, Xw,
                                               tabc, tabs, twc, tws_, 0, 1);
        for (int l = 1; l <= 2; ++l) {
            k_dfthmix<<<bc * 288, 256, 0, stream>>>(Xw, scw, Zb, tabc, tabs, l);
            k_fusedA<<<bc * 256, 256, 0, stream>>>(hbuf, Zb, pww, pwb,
                                                   fc0w, fc0b, hbuf, Xw,
                                                   tabc, tabs, twc, tws_, l, 0);
        }
        k_dfthmix<<<bc * 288, 256, 0, stream>>>(Xw, scw, Zb, tabc, tabs, 3);
        k_fusedB<<<bc * 256, 256, 0, stream>>>(hbuf, Zb, pww, pwb, fc1T, fc1b,
                                               fc2w, fc2b, out + (size_t)b0 * HW,
                                               tabc, tabs);
    }
}

// Round 4
// 4317.386 us; speedup vs baseline: 1.2927x; 1.2927x over previous
//
#include <hip/hip_runtime.h>
#include <hip/hip_bf16.h>
#include <math.h>

#define Hn 256
#define Wn 256
#define Cn 64
#define Mk 12
#define NM 24
#define FCH 128
#define HW 65536

__device__ __forceinline__ float gelu_exact(float x) {
    return 0.5f * x * (1.0f + erff(x * 0.7071067811865476f));
}
__device__ __forceinline__ unsigned short f2bf(float f) {
    __hip_bfloat16 h = __float2bfloat16(f);
    return __builtin_bit_cast(unsigned short, h);
}
__device__ __forceinline__ float bf2f(unsigned short u) {
    unsigned int x = ((unsigned int)u) << 16;
    return __builtin_bit_cast(float, x);
}

// ---------------- tables ----------------
__global__ __launch_bounds__(256) void k_init_tables(float* tc, float* ts,
                                                     float* twc, float* tws) {
    int i = threadIdx.x;  // 0..255
    const float step = 0.024543692606170259f;  // 2*pi/256
    tc[i] = cosf(i * step);
    ts[i] = sinf(i * step);
    for (int k = 0; k < Mk; ++k) {
        int idx = (i * k) & 255;
        twc[i * Mk + k] = cosf(idx * step);
        tws[i * Mk + k] = sinf(idx * step);
    }
}

// ------- spectral weight transpose: scw[l,j,i,o,kx,ky,2] -> scwT[l,j,kx,ky,i,o,2]
__global__ __launch_bounds__(256) void k_prep_w(const float* __restrict__ scw,
                                                float* __restrict__ scwT) {
    int t = blockIdx.x * 256 + threadIdx.x;  // < 4,718,592
    int o  = t & 63;
    int i  = (t >> 6) & 63;
    int r  = t >> 12;           // lj*144 + kx*12 + ky, r < 1152
    int ky = r % Mk;
    int kx = (r / Mk) % Mk;
    int lj = r / 144;           // 0..7
    size_t in_idx = ((((size_t)lj * 64 + i) * 64 + o) * 144) + kx * Mk + ky;
    scwT[2 * (size_t)t]     = scw[2 * in_idx];
    scwT[2 * (size_t)t + 1] = scw[2 * in_idx + 1];
}

// ------- DFT along W of x (all 16 batches, 4096 rows), lane-per-row -------
__global__ __launch_bounds__(64) void k_dftw_x(const float* __restrict__ x,
                                               float* __restrict__ Xxw,
                                               const float* __restrict__ twc,
                                               const float* __restrict__ tws) {
    int r = blockIdx.x * 64 + threadIdx.x;  // 0..4095
    const float* hp = x + (size_t)r * Wn;
    float xr[Mk], xi[Mk];
#pragma unroll
    for (int k = 0; k < Mk; ++k) { xr[k] = 0.f; xi[k] = 0.f; }
    for (int w4 = 0; w4 < 64; ++w4) {
        float4 v = ((const float4*)hp)[w4];
        float vv[4] = {v.x, v.y, v.z, v.w};
#pragma unroll
        for (int j = 0; j < 4; ++j) {
            int wbase = (w4 * 4 + j) * Mk;  // wave-uniform -> scalar loads
#pragma unroll
            for (int k = 0; k < Mk; ++k) {
                xr[k] += vv[j] * twc[wbase + k];
                xi[k] -= vv[j] * tws[wbase + k];
            }
        }
    }
    float* op = Xxw + (size_t)r * (2 * Mk);
#pragma unroll
    for (int k = 0; k < Mk; ++k) { op[2 * k] = xr[k]; op[2 * k + 1] = xi[k]; }
}

// ------- DFT along H of x-modes -> Xfx[b][m][ky] (all batches) -------
__global__ __launch_bounds__(256) void k_xdfth(const float* __restrict__ Xxw,
                                               float* __restrict__ Xfx,
                                               const float* __restrict__ tc,
                                               const float* __restrict__ ts) {
    int t = blockIdx.x * 256 + threadIdx.x;  // < 4608
    if (t >= 16 * 288) return;
    int ky = t % Mk;
    int m  = (t / Mk) % NM;
    int b  = t / 288;
    int kx = (m < Mk) ? m : (232 + m);
    const float* base = Xxw + (size_t)b * Hn * 2 * Mk + 2 * ky;
    float ar = 0.f, ai = 0.f;
    for (int hh = 0; hh < Hn; ++hh) {
        float vr = base[hh * 2 * Mk];
        float vi = base[hh * 2 * Mk + 1];
        int idx = (kx * hh) & 255;
        float c = tc[idx], s = ts[idx];
        ar += vr * c + vi * s;   // * e^{-i theta}
        ai += vi * c - vr * s;
    }
    Xfx[2 * t] = ar;
    Xfx[2 * t + 1] = ai;
}

// ------- layer-0 mix: Z[b][mk][o] from Xfx (lift folded in) -------
__global__ __launch_bounds__(256, 2) void k_mix0(const float* __restrict__ Xfx,
                                                 const float* __restrict__ scwT,
                                                 const float* __restrict__ w0,
                                                 const float* __restrict__ b0v,
                                                 float* __restrict__ Z, int b0) {
    __shared__ float red[512];
    int blk = blockIdx.x;
    int b = blk / 288, mk = blk % 288;
    int m = mk / Mk, ky = mk % Mk;
    int t = threadIdx.x;
    int o = t & 63, q = t >> 6;
    float xr = Xfx[((b0 + b) * 288 + mk) * 2];
    float xi = Xfx[((b0 + b) * 288 + mk) * 2 + 1];
    int j = (m < Mk) ? 0 : 1;
    int kxw = (m < Mk) ? m : (m - Mk);
    const float* wb = scwT + ((size_t)((j * Mk + kxw) * Mk + ky) * 4096 + (q * 16) * 64 + o) * 2;
    float zr = 0.f, zi = 0.f;
#pragma unroll
    for (int ii = 0; ii < 16; ++ii) {
        int i = q * 16 + ii;
        float ar = w0[i] * xr, ai = w0[i] * xi;
        if (mk == 0) ar += 65536.0f * b0v[i];
        float wr = wb[ii * 128], wi = wb[ii * 128 + 1];
        zr += ar * wr - ai * wi;
        zi += ar * wi + ai * wr;
    }
    red[t * 2] = zr; red[t * 2 + 1] = zi;
    __syncthreads();
    if (t < 64) {
        float sr = red[t * 2] + red[(t + 64) * 2] + red[(t + 128) * 2] + red[(t + 192) * 2];
        float si = red[t * 2 + 1] + red[(t + 64) * 2 + 1] + red[(t + 128) * 2 + 1] + red[(t + 192) * 2 + 1];
        const float sc = 2.0f / 65536.0f;  // hermitian 2x + 1/(H*W)
        Z[((size_t)(b * 288 + mk) * 64 + t) * 2] = sr * sc;
        Z[((size_t)(b * 288 + mk) * 64 + t) * 2 + 1] = si * sc;
    }
}

// ------- layers 1..3: dft_h(Xw) + mode mix, fused. Xw layout [b][kappa][hh][i]
__global__ __launch_bounds__(256, 2) void k_dfthmix(const float* __restrict__ Xw,
                                                    const float* __restrict__ scwT,
                                                    float* __restrict__ Z,
                                                    const float* __restrict__ tc,
                                                    const float* __restrict__ ts, int l) {
    __shared__ float red[512];
    __shared__ float xf[128];
    int blk = blockIdx.x;
    int b = blk / 288, mk = blk % 288;
    int m = mk / Mk, ky = mk % Mk;
    int t = threadIdx.x;
    int kx = (m < Mk) ? m : (232 + m);
    int i = t & 63, q = t >> 6;
    // phase 1: Xf[i] = sum_hh Xw[2ky][hh][i] ± ... * e^{-i kx hh}  (coalesced)
    const float* bre = Xw + (size_t)b * 393216 + (size_t)(2 * ky) * 16384;
    const float* bim = bre + 16384;
    float ar = 0.f, ai = 0.f;
    for (int hc = 0; hc < 64; ++hc) {
        int hh = q * 64 + hc;
        float vr = bre[hh * 64 + i];
        float vi = bim[hh * 64 + i];
        int idx = (kx * hh) & 255;
        float c = tc[idx], s = ts[idx];
        ar += vr * c + vi * s;
        ai += vi * c - vr * s;
    }
    red[t * 2] = ar; red[t * 2 + 1] = ai;
    __syncthreads();
    if (t < 64) {
        xf[t * 2]     = red[t * 2] + red[(t + 64) * 2] + red[(t + 128) * 2] + red[(t + 192) * 2];
        xf[t * 2 + 1] = red[t * 2 + 1] + red[(t + 64) * 2 + 1] + red[(t + 128) * 2 + 1] + red[(t + 192) * 2 + 1];
    }
    __syncthreads();
    // phase 2: Z[o] = sum_i W[i][o] * Xf[i]  (contiguous float2 weight reads)
    int o = t & 63;
    int j = (m < Mk) ? 0 : 1;
    int kxw = (m < Mk) ? m : (m - Mk);
    const float* wb = scwT + ((size_t)(((l * 2 + j) * Mk + kxw) * Mk + ky) * 4096 + (q * 16) * 64 + o) * 2;
    float zr = 0.f, zi = 0.f;
#pragma unroll
    for (int ii = 0; ii < 16; ++ii) {
        float br = xf[(q * 16 + ii) * 2], bi = xf[(q * 16 + ii) * 2 + 1];
        float wr = wb[ii * 128], wi = wb[ii * 128 + 1];
        zr += br * wr - bi * wi;
        zi += br * wi + bi * wr;
    }
    __syncthreads();
    red[t * 2] = zr; red[t * 2 + 1] = zi;
    __syncthreads();
    if (t < 64) {
        float sr = red[t * 2] + red[(t + 64) * 2] + red[(t + 128) * 2] + red[(t + 192) * 2];
        float si = red[t * 2 + 1] + red[(t + 64) * 2 + 1] + red[(t + 128) * 2 + 1] + red[(t + 192) * 2 + 1];
        const float sc = 2.0f / 65536.0f;
        Z[((size_t)(b * 288 + mk) * 64 + t) * 2] = sr * sc;
        Z[((size_t)(b * 288 + mk) * 64 + t) * 2 + 1] = si * sc;
    }
}

// ------- fused A: idft_h + idft_w + pointwise + gelu + dft_w(h_new) -------
// xh/hn may alias (in-place, per-fiber, reads precede writes).
__global__ __launch_bounds__(256) void k_fusedA(const float* xh,
        const float* __restrict__ Zb, const float* __restrict__ pww,
        const float* __restrict__ pwb, const float* __restrict__ w0,
        const float* __restrict__ b0v, float* hn, float* __restrict__ XwOut,
        const float* __restrict__ tc, const float* __restrict__ ts,
        const float* __restrict__ twc, const float* __restrict__ tws,
        int l, int first) {
    __shared__ float Ysh[1536];
    __shared__ unsigned short hsh[64 * 272];  // bf16, padded stride 272
    int b  = blockIdx.x >> 8;
    int hh = blockIdx.x & 255;
    int w  = threadIdx.x;
    const float* Zp = Zb + (size_t)b * 288 * 64 * 2;
#pragma unroll
    for (int r3 = 0; r3 < 3; ++r3) {
        int p = w + 256 * r3;          // p = o*12 + ky
        int o = p / Mk, ky = p % Mk;
        float yr = 0.f, yi = 0.f;
#pragma unroll
        for (int m = 0; m < NM; ++m) {
            int kx = (m < Mk) ? m : (232 + m);
            int idx = (kx * hh) & 255;
            float c = tc[idx], s = ts[idx];
            float zr = Zp[((m * Mk + ky) * 64 + o) * 2];
            float zi = Zp[((m * Mk + ky) * 64 + o) * 2 + 1];
            yr += zr * c - zi * s;
            yi += zr * s + zi * c;
        }
        Ysh[p * 2] = yr; Ysh[p * 2 + 1] = yi;
    }
    __syncthreads();
    float cwv[Mk], swv[Mk];
#pragma unroll
    for (int k = 0; k < Mk; ++k) {
        int idx = (k * w) & 255;
        cwv[k] = tc[idx]; swv[k] = ts[idx];
    }
    float acc[Cn];
#pragma unroll
    for (int o = 0; o < Cn; ++o) {
        const float* yp = Ysh + o * 24;
        float a = pwb[l * Cn + o] + 0.5f * yp[0];
#pragma unroll
        for (int k = 1; k < Mk; ++k)
            a += yp[2 * k] * cwv[k] - yp[2 * k + 1] * swv[k];
        acc[o] = a;
    }
    const float* wwb = pww + l * Cn * Cn;
    if (first) {
        float xv = xh[(size_t)b * HW + hh * 256 + w];
#pragma unroll 1
        for (int ic = 0; ic < 4; ++ic) {
            float v[16];
#pragma unroll
            for (int j2 = 0; j2 < 16; ++j2)
                v[j2] = w0[ic * 16 + j2] * xv + b0v[ic * 16 + j2];
#pragma unroll
            for (int o = 0; o < Cn; ++o) {
                const float* wr = wwb + o * Cn + ic * 16;  // uniform -> s_load
                float a = acc[o];
#pragma unroll
                for (int j2 = 0; j2 < 16; ++j2) a += v[j2] * wr[j2];
                acc[o] = a;
            }
        }
    } else {
        const float* hb = xh + (size_t)b * Cn * HW + hh * 256 + w;
#pragma unroll 1
        for (int ic = 0; ic < 4; ++ic) {
            float v[16];
#pragma unroll
            for (int j2 = 0; j2 < 16; ++j2)
                v[j2] = hb[(size_t)(ic * 16 + j2) * HW];
#pragma unroll
            for (int o = 0; o < Cn; ++o) {
                const float* wr = wwb + o * Cn + ic * 16;
                float a = acc[o];
#pragma unroll
                for (int j2 = 0; j2 < 16; ++j2) a += v[j2] * wr[j2];
                acc[o] = a;
            }
        }
    }
    // gelu + store h (fp32) + stage bf16 into LDS; acc dies here -> no spill
    float* ob = hn + (size_t)b * Cn * HW + hh * 256 + w;
#pragma unroll
    for (int o = 0; o < Cn; ++o) {
        float g = gelu_exact(acc[o]);
        ob[(size_t)o * HW] = g;
        hsh[o * 272 + w] = f2bf(g);
    }
    __syncthreads();
    // DFT along W of h_new -> Xw[b][kappa][hh][i]  (bf16 source, x1-path only)
    float* Xwb = XwOut + (size_t)b * 393216;
#pragma unroll 1
    for (int r2 = 0; r2 < 3; ++r2) {
        int p = w + 256 * r2;          // p = o2*12 + ky, < 768
        int o2 = p / Mk, ky = p % Mk;
        const unsigned short* row = hsh + o2 * 272;
        float xr = 0.f, xi = 0.f;
        for (int wi2 = 0; wi2 < Wn; ++wi2) {
            float hv = bf2f(row[wi2]);
            xr += hv * twc[wi2 * Mk + ky];
            xi -= hv * tws[wi2 * Mk + ky];
        }
        Xwb[(size_t)(2 * ky) * 16384 + hh * 64 + o2] = xr;
        Xwb[(size_t)(2 * ky + 1) * 16384 + hh * 64 + o2] = xi;
    }
}

// ------- fused B (layer 3): idft + pointwise + fc1/gelu/fc2 (d-tiled) -------
__global__ __launch_bounds__(256) void k_fusedB(const float* __restrict__ h,
        const float* __restrict__ Zb, const float* __restrict__ pww,
        const float* __restrict__ pwb, const float* __restrict__ fc1w,
        const float* __restrict__ fc1b, const float* __restrict__ fc2w,
        const float* __restrict__ fc2b, float* __restrict__ outp,
        const float* __restrict__ tc, const float* __restrict__ ts) {
    __shared__ float Ysh[1536];
    int b  = blockIdx.x >> 8;
    int hh = blockIdx.x & 255;
    int w  = threadIdx.x;
    const float* Zp = Zb + (size_t)b * 288 * 64 * 2;
#pragma unroll
    for (int r3 = 0; r3 < 3; ++r3) {
        int p = w + 256 * r3;
        int o = p / Mk, ky = p % Mk;
        float yr = 0.f, yi = 0.f;
#pragma unroll
        for (int m = 0; m < NM; ++m) {
            int kx = (m < Mk) ? m : (232 + m);
            int idx = (kx * hh) & 255;
            float c = tc[idx], s = ts[idx];
            float zr = Zp[((m * Mk + ky) * 64 + o) * 2];
            float zi = Zp[((m * Mk + ky) * 64 + o) * 2 + 1];
            yr += zr * c - zi * s;
            yi += zr * s + zi * c;
        }
        Ysh[p * 2] = yr; Ysh[p * 2 + 1] = yi;
    }
    __syncthreads();
    float cwv[Mk], swv[Mk];
#pragma unroll
    for (int k = 0; k < Mk; ++k) {
        int idx = (k * w) & 255;
        cwv[k] = tc[idx]; swv[k] = ts[idx];
    }
    float acc[Cn];
#pragma unroll
    for (int o = 0; o < Cn; ++o) {
        const float* yp = Ysh + o * 24;
        float a = pwb[3 * Cn + o] + 0.5f * yp[0];
#pragma unroll
        for (int k = 1; k < Mk; ++k)
            a += yp[2 * k] * cwv[k] - yp[2 * k + 1] * swv[k];
        acc[o] = a;
    }
    const float* wwb = pww + 3 * Cn * Cn;
    const float* hb = h + (size_t)b * Cn * HW + hh * 256 + w;
#pragma unroll 1
    for (int ic = 0; ic < 4; ++ic) {
        float v[16];
#pragma unroll
        for (int j2 = 0; j2 < 16; ++j2)
            v[j2] = hb[(size_t)(ic * 16 + j2) * HW];
#pragma unroll
        for (int o = 0; o < Cn; ++o) {
            const float* wr = wwb + o * Cn + ic * 16;
            float a = acc[o];
#pragma unroll
            for (int j2 = 0; j2 < 16; ++j2) a += v[j2] * wr[j2];
            acc[o] = a;
        }
    }
    // fc1 -> gelu -> fc2, d tiled by 32: 32 independent accumulators (ILP)
    float outv = fc2b[0];
#pragma unroll 1
    for (int dt = 0; dt < 4; ++dt) {
        float hid[32];
#pragma unroll
        for (int j2 = 0; j2 < 32; ++j2) hid[j2] = fc1b[dt * 32 + j2];
#pragma unroll 8
        for (int o = 0; o < Cn; ++o) {
            float a = acc[o];
            const float* wr = fc1w + o * FCH + dt * 32;  // uniform -> s_load
#pragma unroll
            for (int j2 = 0; j2 < 32; ++j2) hid[j2] += a * wr[j2];
        }
#pragma unroll
        for (int j2 = 0; j2 < 32; ++j2)
            outv += gelu_exact(hid[j2]) * fc2w[dt * 32 + j2];
    }
    outp[(size_t)b * HW + hh * 256 + w] = outv;
}

extern "C" void kernel_launch(void* const* d_in, const int* in_sizes, int n_in,
                              void* d_out, int out_size, void* d_ws, size_t ws_size,
                              hipStream_t stream) {
    const float* x    = (const float*)d_in[0];
    const float* fc0w = (const float*)d_in[1];
    const float* fc0b = (const float*)d_in[2];
    const float* scw  = (const float*)d_in[3];
    const float* pww  = (const float*)d_in[4];
    const float* pwb  = (const float*)d_in[5];
    const float* fc1w = (const float*)d_in[6];
    const float* fc1b = (const float*)d_in[7];
    const float* fc2w = (const float*)d_in[8];
    const float* fc2b = (const float*)d_in[9];
    float* out = (float*)d_out;
    float* ws  = (float*)d_ws;

    // base: tables 6656 + Xfx 9216 + scwT 9,437,184 = 9,453,056 floats
    // per batch: h 4,194,304 + Xw 393,216 + Z 36,864 = 4,624,384 floats
    const size_t basef = 9453056;
    const size_t perbf = 4624384;
    int bc = 0;
    for (int cand = 16; cand >= 1; cand >>= 1)
        if ((basef + perbf * (size_t)cand) * 4 <= ws_size) { bc = cand; break; }
    if (bc == 0) return;  // diagnosable: zero output

    float* tabc = ws;
    float* tabs = tabc + 256;
    float* twc  = tabs + 256;
    float* tws_ = twc + 3072;
    float* Xfx  = tws_ + 3072;          // 9216
    float* scwT = Xfx + 9216;           // 9,437,184
    float* hbuf = ws + basef;           // bc*4,194,304 (also Xxw temp 98,304)
    float* Xw   = hbuf + (size_t)bc * 4194304;
    float* Zb   = Xw + (size_t)bc * 393216;

    k_init_tables<<<1, 256, 0, stream>>>(tabc, tabs, twc, tws_);
    k_prep_w<<<18432, 256, 0, stream>>>(scw, scwT);
    k_dftw_x<<<64, 64, 0, stream>>>(x, hbuf, twc, tws_);
    k_xdfth<<<18, 256, 0, stream>>>(hbuf, Xfx, tabc, tabs);

    for (int b0 = 0; b0 < 16; b0 += bc) {
        k_mix0<<<bc * 288, 256, 0, stream>>>(Xfx, scwT, fc0w, fc0b, Zb, b0);
        k_fusedA<<<bc * 256, 256, 0, stream>>>(x + (size_t)b0 * HW, Zb, pww, pwb,
                                               fc0w, fc0b, hbuf, Xw,
                                               tabc, tabs, twc, tws_, 0, 1);
        for (int l = 1; l <= 2; ++l) {
            k_dfthmix<<<bc * 288, 256, 0, stream>>>(Xw, scwT, Zb, tabc, tabs, l);
            k_fusedA<<<bc * 256, 256, 0, stream>>>(hbuf, Zb, pww, pwb,
                                                   fc0w, fc0b, hbuf, Xw,
                                                   tabc, tabs, twc, tws_, l, 0);
        }
        k_dfthmix<<<bc * 288, 256, 0, stream>>>(Xw, scwT, Zb, tabc, tabs, 3);
        k_fusedB<<<bc * 256, 256, 0, stream>>>(hbuf, Zb, pww, pwb, fc1w, fc1b,
                                               fc2w, fc2b, out + (size_t)b0 * HW,
                                               tabc, tabs);
    }
}